// Round 5
// baseline (256.473 us; speedup 1.0000x reference)
//
#include <hip/hip_runtime.h>
#include <math.h>

typedef int v4i  __attribute__((ext_vector_type(4)));
typedef int v16i __attribute__((ext_vector_type(16)));

#define DIM 4096
#define BT 128
#define KT 64           // K-tile bytes (int8): dbuf LDS = 32 KB -> 5 blocks/CU
#define TILE (BT * KT)  // 8192 B per A/B tile

// ---------------------------------------------------------------------------
// async global->LDS 16B copy (wave-uniform base + lane*16 destination rule)
// ---------------------------------------------------------------------------
__device__ __forceinline__ void async16(const void* g, void* l) {
    __builtin_amdgcn_global_load_lds((__attribute__((address_space(1))) void*)(g),
                                     (__attribute__((address_space(3))) void*)(l),
                                     16, 0, 0);
}

// ---------------------------------------------------------------------------
// Fused prep (unchanged): blocks [0,4096) FWHT(256)+int4 quant of one x row;
// blocks [4096,20480) narrow int32 weights to int8.
// ---------------------------------------------------------------------------
__global__ __launch_bounds__(256) void prep(const float* __restrict__ x,
                                            const int* __restrict__ w,
                                            signed char* __restrict__ q,
                                            signed char* __restrict__ w8,
                                            float* __restrict__ scales) {
    if (blockIdx.x >= 4096) {
        int i = (blockIdx.x - 4096) * 256 + threadIdx.x;
        int4 v = ((const int4*)w)[i];
        char4 c;
        c.x = (signed char)v.x; c.y = (signed char)v.y;
        c.z = (signed char)v.z; c.w = (signed char)v.w;
        ((char4*)w8)[i] = c;
        return;
    }
    const int row  = blockIdx.x;
    const int lane = threadIdx.x & 63;
    const int wave = threadIdx.x >> 6;
    const float4* xr4 = (const float4*)(x + (size_t)row * DIM);

    float sgn[6];
    #pragma unroll
    for (int i = 0; i < 6; ++i) sgn[i] = (lane & (1 << i)) ? -1.0f : 1.0f;

    float f[4][4];
    #pragma unroll
    for (int b = 0; b < 4; ++b) {
        const int blk = wave + 4 * b;
        float4 v = xr4[blk * 64 + lane];
        float t0 = v.x + v.y, t1 = v.x - v.y;
        float t2 = v.z + v.w, t3 = v.z - v.w;
        f[b][0] = t0 + t2; f[b][1] = t1 + t3;
        f[b][2] = t0 - t2; f[b][3] = t1 - t3;
        #pragma unroll
        for (int st = 0; st < 6; ++st) {
            const int m = 1 << st;
            #pragma unroll
            for (int j = 0; j < 4; ++j) {
                float p = __shfl_xor(f[b][j], m, 64);
                f[b][j] = fmaf(sgn[st], f[b][j], p);
            }
        }
        #pragma unroll
        for (int j = 0; j < 4; ++j) f[b][j] *= 0.0625f;   // / sqrt(256)
    }

    float m = 0.0f;
    #pragma unroll
    for (int b = 0; b < 4; ++b)
        #pragma unroll
        for (int j = 0; j < 4; ++j) m = fmaxf(m, fabsf(f[b][j]));
    #pragma unroll
    for (int d = 32; d; d >>= 1) m = fmaxf(m, __shfl_xor(m, d, 64));
    __shared__ float sm[4];
    if (lane == 0) sm[wave] = m;
    __syncthreads();
    m = fmaxf(fmaxf(sm[0], sm[1]), fmaxf(sm[2], sm[3]));

    const float s = m / 7.0f;                 // exact-match reference scale
    if (threadIdx.x == 0) scales[row] = s;

    char4* qr4 = (char4*)(q + (size_t)row * DIM);
    #pragma unroll
    for (int b = 0; b < 4; ++b) {
        const int blk = wave + 4 * b;
        char4 c;
        int qi;
        qi = (int)rintf(f[b][0] / s); c.x = (signed char)min(7, max(-8, qi));
        qi = (int)rintf(f[b][1] / s); c.y = (signed char)min(7, max(-8, qi));
        qi = (int)rintf(f[b][2] / s); c.z = (signed char)min(7, max(-8, qi));
        qi = (int)rintf(f[b][3] / s); c.w = (signed char)min(7, max(-8, qi));
        qr4[blk * 64 + lane] = c;
    }
}

// ---------------------------------------------------------------------------
// int8 GEMM, double-buffered, KT=64 for occupancy.
// LDS: [A0|B0|A1|B1] x 8 KB = 32 KB -> 5 blocks/CU by LDS (work gives 4 =
// 16 waves/CU = 4 waves/SIMD vs 1.5 at R4's 64 KB). One barrier per K-tile,
// order: barrier -> stage(next, other buf) -> compute(this buf).
// 64 B LDS rows, chunk swizzle ^(r&3): 32x32-frag b128 reads cover all 8
// bank-quads x 8 lanes -> minimal 8 sweeps (throughput-conflict-free).
// ---------------------------------------------------------------------------
__global__ __launch_bounds__(256) void gemm_q8(const signed char* __restrict__ A,
                                               const signed char* __restrict__ B,
                                               const float* __restrict__ rowScale,
                                               const float* __restrict__ wscale,
                                               const float* __restrict__ bias,
                                               float* __restrict__ out) {
    __shared__ __align__(16) signed char S[4 * TILE];   // 32 KB

    const int bm = blockIdx.y, bn = blockIdx.x;
    const int t = threadIdx.x;
    const int lane = t & 63, wave = t >> 6;
    const int wm = (wave >> 1) * 64, wn = (wave & 1) * 64;
    const int l31 = lane & 31, lh = lane >> 5;

    // running global staging pointers (advance KT per staged tile)
    // per matrix-tile: 512 chunks of 16 B -> 2 per thread
    const signed char* ga[2];
    const signed char* gb[2];
    #pragma unroll
    for (int h = 0; h < 2; ++h) {
        const int cidx = t + 256 * h;             // 0..511
        const int row  = cidx >> 2;               // 0..127
        const int g    = (cidx & 3) ^ (row & 3);  // swizzled global chunk
        ga[h] = A + (size_t)(bm * BT + row) * DIM + g * 16;
        gb[h] = B + (size_t)(bn * BT + row) * DIM + g * 16;
    }

    // loop-invariant per-lane LDS byte offsets (buffer picked by imm const)
    int offA[2][2], offB[2][2];
    #pragma unroll
    for (int i = 0; i < 2; ++i)
        #pragma unroll
        for (int s = 0; s < 2; ++s) {
            const int r  = wm + i * 32 + l31;
            const int c  = wn + i * 32 + l31;
            const int cl = 2 * s + lh;            // logical 16B chunk (k-step s)
            offA[i][s] = r * KT + ((cl ^ (r & 3)) * 16);
            offB[i][s] = c * KT + ((cl ^ (c & 3)) * 16) + TILE;
        }

    v16i acc[2][2] = {};

#define STAGE(P) do {                                                          \
        _Pragma("unroll")                                                      \
        for (int h = 0; h < 2; ++h) {                                          \
            const int l = (P) * 2 * TILE + (t + 256 * h) * 16;                 \
            async16(ga[h], &S[l]);        ga[h] += KT;                         \
            async16(gb[h], &S[l + TILE]); gb[h] += KT;                         \
        }                                                                      \
    } while (0)

#define COMPUTE(P) do {                                                        \
        _Pragma("unroll")                                                      \
        for (int s = 0; s < 2; ++s) {                                          \
            const v4i a0 = *(const v4i*)&S[(P) * 2 * TILE + offA[0][s]];       \
            const v4i a1 = *(const v4i*)&S[(P) * 2 * TILE + offA[1][s]];       \
            const v4i b0 = *(const v4i*)&S[(P) * 2 * TILE + offB[0][s]];       \
            const v4i b1 = *(const v4i*)&S[(P) * 2 * TILE + offB[1][s]];       \
            acc[0][0] = __builtin_amdgcn_mfma_i32_32x32x32_i8(a0, b0, acc[0][0], 0, 0, 0); \
            acc[0][1] = __builtin_amdgcn_mfma_i32_32x32x32_i8(a0, b1, acc[0][1], 0, 0, 0); \
            acc[1][0] = __builtin_amdgcn_mfma_i32_32x32x32_i8(a1, b0, acc[1][0], 0, 0, 0); \
            acc[1][1] = __builtin_amdgcn_mfma_i32_32x32x32_i8(a1, b1, acc[1][1], 0, 0, 0); \
        }                                                                      \
    } while (0)

    // 64 K-tiles: stage #n -> buffer n&1; compute tile n from buffer n&1.
    STAGE(0);                                  // tile 0 -> buf0
    #pragma unroll 1
    for (int it = 0; it < 31; ++it) {
        __syncthreads(); STAGE(1); COMPUTE(0);
        __syncthreads(); STAGE(0); COMPUTE(1);
    }
    __syncthreads(); STAGE(1); COMPUTE(0);     // tile 62 compute, 63 stage
    __syncthreads();           COMPUTE(1);     // tile 63 compute

#undef STAGE
#undef COMPUTE

    // epilogue: out[n,o] = acc * sx[n] * ws[o] + bias[o]
    // C/D: col = lane&31, row = (reg&3) + 8*(reg>>2) + 4*(lane>>5)  [m74/m101]
    #pragma unroll
    for (int j = 0; j < 2; ++j) {
        const int col = bn * BT + wn + j * 32 + l31;
        const float ws = wscale[col];
        const float bs = bias[col];
        #pragma unroll
        for (int i = 0; i < 2; ++i) {
            const int rb = bm * BT + wm + i * 32 + 4 * lh;
            #pragma unroll
            for (int r = 0; r < 16; ++r) {
                const int row = rb + (r & 3) + 8 * (r >> 2);
                out[(size_t)row * DIM + col] =
                    ((float)acc[i][j][r] * rowScale[row]) * ws + bs;
            }
        }
    }
}

// ---------------------------------------------------------------------------
extern "C" void kernel_launch(void* const* d_in, const int* in_sizes, int n_in,
                              void* d_out, int out_size, void* d_ws, size_t ws_size,
                              hipStream_t stream) {
    const float* x      = (const float*)d_in[0];
    const int*   wint   = (const int*)d_in[1];
    const float* wscale = (const float*)d_in[2];
    const float* bias   = (const float*)d_in[3];
    float* out = (float*)d_out;

    signed char* q8 = (signed char*)d_ws;                         // 16 MB
    signed char* w8 = q8 + (size_t)DIM * DIM;                     // 16 MB
    float* sx = (float*)(w8 + (size_t)DIM * DIM);                 // 16 KB

    prep<<<4096 + 16384, 256, 0, stream>>>(x, wint, q8, w8, sx);
    gemm_q8<<<dim3(DIM / BT, DIM / BT), 256, 0, stream>>>(q8, w8, sx, wscale, bias, out);
}